// Round 19
// baseline (52.734 us; speedup 1.0000x reference)
//
#include <hip/hip_runtime.h>

typedef __attribute__((ext_vector_type(8))) short short8;
typedef __attribute__((ext_vector_type(4))) float f32x4;

#define HH 128
#define WW 128
#define TW 16
#define TH 8
#define HALOW 18
#define HALOH 10
#define NPIX (HALOW * HALOH)   // 180
#define NA (9 * TH * TW)       // 1152 floats per buffer

typedef __attribute__((address_space(1))) const unsigned int glds_src_t;
typedef __attribute__((address_space(3))) unsigned int glds_dst_t;

__device__ inline unsigned short f2bf(float f) {
    unsigned int u = __builtin_bit_cast(unsigned int, f);
    u += 0x7fffu + ((u >> 16) & 1u);   // round-to-nearest-even
    return (unsigned short)(u >> 16);
}

// ---------------- kernel A: x -> xT (bf16, pixel-major) + partial means + W3 ----
// W3 layout: flat ushort idx (((t*2+ks)*4+lk)*64 + m)*8 + j, c = ks*32+lk*8+j.
__global__ __launch_bounds__(256) void prep_kernel(
    const float* __restrict__ x, const float* __restrict__ wgt,
    unsigned short* __restrict__ xT, float* __restrict__ partials,
    unsigned short* __restrict__ W3, float* __restrict__ zpage) {
    const int id = blockIdx.x;
    const int tid = threadIdx.x;
    if (id == 0 && tid < 32) zpage[tid] = 0.f;   // 128B zero page for OOB DMA
    {
        int i = id * 256 + tid;
        if (i < 64 * 64 * 9) {
            int j = i & 7, rest = i >> 3;
            int m = rest & 63; rest >>= 6;
            int lk = rest & 3; rest >>= 2;
            int ks = rest & 1, t = rest >> 1;
            int c = ks * 32 + lk * 8 + j;
            W3[i] = f2bf(wgt[(m * 64 + c) * 9 + t]);
        }
    }
    const int b = id & 7, pt = id >> 3;
    const int p0 = pt * 64;
    __shared__ unsigned int lt[64 * 33];
    __shared__ float red[8][32][2];

    const int px = tid & 63, cp0 = tid >> 6;
    const float* xb = x + (size_t)b * 64 * (HH * WW) + p0 + px;
    #pragma unroll
    for (int i = 0; i < 8; ++i) {
        int cp = cp0 + 4 * i;
        float v0 = xb[(size_t)(2 * cp) * (HH * WW)];
        float v1 = xb[(size_t)(2 * cp + 1) * (HH * WW)];
        lt[px * 33 + cp] = (unsigned)f2bf(v0) | ((unsigned)f2bf(v1) << 16);
    }
    __syncthreads();
    #pragma unroll
    for (int it = 0; it < 2; ++it) {
        int idx = it * 256 + tid;
        int p = idx >> 3, ch = idx & 7;
        int o = p * 33 + ch * 4;
        uint4 v = make_uint4(lt[o], lt[o + 1], lt[o + 2], lt[o + 3]);
        *(uint4*)(xT + ((size_t)(b * (HH * WW) + p0 + p) * 64 + ch * 8)) = v;
    }
    {
        int cp = tid & 31, grp = tid >> 5;
        float s0 = 0.f, s1 = 0.f;
        #pragma unroll
        for (int j2 = 0; j2 < 8; ++j2) {
            unsigned u = lt[(grp * 8 + j2) * 33 + cp];
            s0 += __builtin_bit_cast(float, u << 16);
            s1 += __builtin_bit_cast(float, u & 0xffff0000u);
        }
        red[grp][cp][0] = s0;
        red[grp][cp][1] = s1;
    }
    __syncthreads();
    if (tid < 64) {
        float s = 0.f;
        #pragma unroll
        for (int g2 = 0; g2 < 8; ++g2) s += red[g2][tid >> 1][tid & 1];
        partials[(size_t)(b * 256 + pt) * 64 + tid] = s;
    }
}

// ---------------- kernel C: fused MLP + main dynamic conv (counted-vmcnt) ----
// R16 structure with ONE change: TH 4->8 (task = 16x8 px, halo 18x10).
// Per block: 2 iterations instead of 4 -> half the barrier/vmcnt/STAGE
// events per unit work; halo rows 4,5 no longer staged-read twice.
// av is computed on the fly from LDS (broadcast b32) to keep VGPR ~170.
__global__ __launch_bounds__(256, 1) void main_kernel(
    const unsigned short* __restrict__ xT, const float* __restrict__ atw1,
    const unsigned short* __restrict__ W3, const float* __restrict__ partials,
    const float* __restrict__ a2w1, const float* __restrict__ a2b1,
    const float* __restrict__ a2w2, const float* __restrict__ a2b2,
    const float* __restrict__ a3w1, const float* __restrict__ a3b1,
    const float* __restrict__ a3w2, const float* __restrict__ a3b2,
    float* __restrict__ out, const float* __restrict__ zpage) {
    const int id = blockIdx.x;
    const int b = id & 7;
    const int j = id >> 3;        // 0..63 -> tasks 2j, 2j+1  (128 tiles/batch)
    const int tid = threadIdx.x;
    const int lane = tid & 63;
    const int wtile = tid >> 6;   // wave id (uniform per wave)
    const int lm = lane & 15;
    const int lk = lane >> 4;

    __shared__ char xsc[2][24576];        // 1536 slots x 16B (1440 used + slack)
    __shared__ float alds[2][1280];       // 1152 used + slack
    __shared__ float rb[4][64];
    __shared__ float gs[64], h3[64], h2[12], rrs[12], bbs[64];

    const char* xbb = (const char*)(xT + (size_t)b * (HH * WW) * 64);
    const float* ab = atw1 + (size_t)b * 9 * (HH * WW);
    float* ob = out + (size_t)b * 64 * (HH * WW);
    const char* zp = (const char*)zpage;

    // ---- async stage of one task into buffer bi (11 DMA issues per thread) ----
    auto STAGE = [&](int bi, int task) {
        const int py0 = (task >> 3) * TH, px0 = (task & 7) * TW;
        #pragma unroll
        for (int i = 0; i < 6; ++i) {
            int idx = i * 256 + tid;               // 0..1535; slot = dest/16
            int pix = idx >> 3, ch = idx & 7;
            int yy = pix / HALOW;
            int xx = pix - yy * HALOW;
            int gy = py0 + yy - 1, gx = px0 + xx - 1;
            bool ok = (pix < NPIX) && (gy >= 0) && (gy < HH) && (gx >= 0) && (gx < WW);
            const char* src = ok
                ? xbb + (((size_t)(gy * WW + gx)) << 7) + ((ch * 16) ^ ((pix & 7) << 4))
                : zp;
            char* dst = &xsc[bi][(i * 256 + wtile * 64) * 16];   // uniform base + lane*16
            __builtin_amdgcn_global_load_lds((glds_src_t*)src, (glds_dst_t*)dst, 16, 0, 0);
        }
        #pragma unroll
        for (int i = 0; i < 5; ++i) {
            int idx = i * 256 + tid;               // 0..1279
            int t = idx >> 7, rem = idx & 127;
            int rr = rem >> 4, cc = rem & 15;
            bool ok = idx < NA;
            const char* src = ok
                ? (const char*)(ab + (size_t)t * (HH * WW) + (py0 + rr) * WW + px0 + cc)
                : zp;
            float* dst = &alds[bi][i * 256 + wtile * 64];
            __builtin_amdgcn_global_load_lds((glds_src_t*)src, (glds_dst_t*)dst, 4, 0, 0);
        }
    };

    // ---- prologue DMA first: MLP compute below hides its latency ----
    STAGE(0, j * 2);

    // ---- W fragments: 18 coalesced b128 loads ----
    short8 wfrag[9][2];
    {
        const short8* W3v = (const short8*)W3;
        #pragma unroll
        for (int t = 0; t < 9; ++t)
            #pragma unroll
            for (int ks = 0; ks < 2; ++ks)
                wfrag[t][ks] = W3v[(((t * 2 + ks) * 4 + lk) * 64) + wtile * 16 + lm];
    }

    // ---- fused MLP: partials -> g -> ratio (rrs), bias (bbs) ----
    {
        const int t = tid & 63, is = tid >> 6;
        float s = 0.f;
        #pragma unroll 8
        for (int k = 0; k < 64; ++k)
            s += partials[(size_t)(b * 256 + is + 4 * k) * 64 + t];
        rb[is][t] = s;
        __syncthreads();
        if (tid < 64)
            gs[t] = (rb[0][t] + rb[1][t] + rb[2][t] + rb[3][t]) * (1.f / (HH * WW));
        __syncthreads();
        if (tid < 64) {
            float s3 = 0.f;
            #pragma unroll 8
            for (int i = 0; i < 64; ++i) s3 += gs[i] * a3w1[t * 64 + i];
            h3[t] = fmaxf(s3 + a3b1[t], 0.f);
            if (t < 9) {
                float s2 = 0.f;
                #pragma unroll 8
                for (int i = 0; i < 64; ++i) s2 += gs[i] * a2w1[t * 64 + i];
                h2[t] = fmaxf(s2 + a2b1[t], 0.f);
            }
        }
        __syncthreads();
        if (tid < 64) {
            float o = 0.f;
            #pragma unroll 8
            for (int i = 0; i < 64; ++i) o += h3[i] * a3w2[t * 64 + i];
            bbs[t] = o + a3b2[t];
            if (t < 9) {
                float r = 0.f;
                #pragma unroll
                for (int i = 0; i < 9; ++i) r += h2[i] * a2w2[t * 9 + i];
                rrs[t] = r + a2b2[t];
            }
        }
        __syncthreads();   // also drains prologue STAGE (vmcnt 0) -> buf0 ready
    }

    float rat[9];
    #pragma unroll
    for (int t = 0; t < 9; ++t) rat[t] = rrs[t];
    float biasr[4];
    #pragma unroll
    for (int q = 0; q < 4; ++q) biasr[q] = bbs[wtile * 16 + lk * 4 + q];

    #pragma unroll 1
    for (int it = 0; it < 2; ++it) {
        if (it < 1) {
            STAGE((it + 1) & 1, j * 2 + it + 1);   // DMA lands under compute
            __builtin_amdgcn_sched_barrier(0);     // pin: all STAGE issues precede stores
        }

        const int task = j * 2 + it;
        const int py0 = (task >> 3) * TH, px0 = (task & 7) * TW;
        const char* xs = xsc[it & 1];
        const float* al = alds[it & 1];

        // ---- single pass: 8 output rows, 10 halo rows, 60 b128 reads ----
        f32x4 yac[8];
        #pragma unroll
        for (int r = 0; r < 8; ++r) yac[r] = (f32x4){0.f, 0.f, 0.f, 0.f};

        #pragma unroll
        for (int hl = 0; hl < 10; ++hl) {
            const int pixr = hl * HALOW + lm;
            short8 bf[3][2];
            #pragma unroll
            for (int dx = 0; dx < 3; ++dx) {
                const int pix = pixr + dx;
                const int sw = (pix & 7) << 4;
                const char* bp2 = xs + pix * 128;
                #pragma unroll
                for (int ks = 0; ks < 2; ++ks)
                    bf[dx][ks] = __builtin_bit_cast(short8,
                        *(const uint4*)(bp2 + ((ks * 64 + lk * 16) ^ sw)));
            }
            #pragma unroll
            for (int dy = 0; dy < 3; ++dy) {
                const int r = hl - dy;
                if (r < 0 || r > 7) continue;
                #pragma unroll
                for (int dx = 0; dx < 3; ++dx) {
                    const int t = dy * 3 + dx;
                    f32x4 z = {0.f, 0.f, 0.f, 0.f};
                    z = __builtin_amdgcn_mfma_f32_16x16x32_bf16(wfrag[t][0], bf[dx][0], z, 0, 0, 0);
                    z = __builtin_amdgcn_mfma_f32_16x16x32_bf16(wfrag[t][1], bf[dx][1], z, 0, 0, 0);
                    const float a = al[t * 128 + r * 16 + lm] * rat[t];
                    #pragma unroll
                    for (int q = 0; q < 4; ++q) yac[r][q] = fmaf(a, z[q], yac[r][q]);
                }
            }
        }
        #pragma unroll
        for (int r = 0; r < 8; ++r) {
            const int pyg = py0 + r;
            #pragma unroll
            for (int q = 0; q < 4; ++q) {
                int m = wtile * 16 + lk * 4 + q;   // D: row=(lane>>4)*4+q, col=lane&15
                ob[((size_t)m * HH + pyg) * WW + px0 + lm] = yac[r][q] + biasr[q];
            }
        }

        if (it < 1) {
            // wait only for the 11 staging DMAs (oldest); 32 stores stay in flight
            asm volatile("s_waitcnt vmcnt(32)" ::: "memory");
            __builtin_amdgcn_s_barrier();
            __builtin_amdgcn_sched_barrier(0);
        }
    }
}

extern "C" void kernel_launch(void* const* d_in, const int* in_sizes, int n_in,
                              void* d_out, int out_size, void* d_ws, size_t ws_size,
                              hipStream_t stream) {
    const float* x    = (const float*)d_in[0];
    const float* atw1 = (const float*)d_in[1];
    const float* wgt  = (const float*)d_in[2];
    const float* a2w1 = (const float*)d_in[3];
    const float* a2b1 = (const float*)d_in[4];
    const float* a2w2 = (const float*)d_in[5];
    const float* a2b2 = (const float*)d_in[6];
    const float* a3w1 = (const float*)d_in[7];
    const float* a3b1 = (const float*)d_in[8];
    const float* a3w2 = (const float*)d_in[9];
    const float* a3b2 = (const float*)d_in[10];
    float* out = (float*)d_out;

    float* ws = (float*)d_ws;
    float* zpage = ws + 640;                                // 32 floats (zeroed by prep)
    unsigned short* W3 = (unsigned short*)(ws + 1024);      // 36864 ushorts
    float* partials = ws + 19456;                           // 131072 floats
    unsigned short* xT = (unsigned short*)(ws + 150528);    // 8388608 ushorts (16.8 MB)

    prep_kernel<<<dim3(2048), dim3(256), 0, stream>>>(x, wgt, xT, partials, W3, zpage);
    main_kernel<<<dim3(512), dim3(256), 0, stream>>>(
        xT, atw1, W3, partials, a2w1, a2b1, a2w2, a2b2,
        a3w1, a3b1, a3w2, a3b2, out, zpage);
}

// Round 20
// 37.341 us; speedup vs baseline: 1.4122x; 1.4122x over previous
//
#include <hip/hip_runtime.h>

typedef __attribute__((ext_vector_type(8))) short short8;
typedef __attribute__((ext_vector_type(4))) float f32x4;

#define HH 128
#define WW 128
#define TW 16
#define TH 4
#define HALOW 18
#define HALOH 6
#define NPIX (HALOW * HALOH)   // 108
#define NA (9 * TH * TW)       // 576 floats per buffer

typedef __attribute__((address_space(1))) const unsigned int glds_src_t;
typedef __attribute__((address_space(3))) unsigned int glds_dst_t;

__device__ inline unsigned short f2bf(float f) {
    unsigned int u = __builtin_bit_cast(unsigned int, f);
    u += 0x7fffu + ((u >> 16) & 1u);   // round-to-nearest-even
    return (unsigned short)(u >> 16);
}

// ---------------- kernel A: x -> xT (bf16, pixel-major) + partial means + W3 ----
// W3 layout: flat ushort idx (((t*2+ks)*4+lk)*64 + m)*8 + j, c = ks*32+lk*8+j.
__global__ __launch_bounds__(256) void prep_kernel(
    const float* __restrict__ x, const float* __restrict__ wgt,
    unsigned short* __restrict__ xT, float* __restrict__ partials,
    unsigned short* __restrict__ W3, float* __restrict__ zpage) {
    const int id = blockIdx.x;
    const int tid = threadIdx.x;
    if (id == 0 && tid < 32) zpage[tid] = 0.f;   // 128B zero page for OOB DMA
    {
        int i = id * 256 + tid;
        if (i < 64 * 64 * 9) {
            int j = i & 7, rest = i >> 3;
            int m = rest & 63; rest >>= 6;
            int lk = rest & 3; rest >>= 2;
            int ks = rest & 1, t = rest >> 1;
            int c = ks * 32 + lk * 8 + j;
            W3[i] = f2bf(wgt[(m * 64 + c) * 9 + t]);
        }
    }
    const int b = id & 7, pt = id >> 3;
    const int p0 = pt * 64;
    __shared__ unsigned int lt[64 * 33];
    __shared__ float red[8][32][2];

    const int px = tid & 63, cp0 = tid >> 6;
    const float* xb = x + (size_t)b * 64 * (HH * WW) + p0 + px;
    #pragma unroll
    for (int i = 0; i < 8; ++i) {
        int cp = cp0 + 4 * i;
        float v0 = xb[(size_t)(2 * cp) * (HH * WW)];
        float v1 = xb[(size_t)(2 * cp + 1) * (HH * WW)];
        lt[px * 33 + cp] = (unsigned)f2bf(v0) | ((unsigned)f2bf(v1) << 16);
    }
    __syncthreads();
    #pragma unroll
    for (int it = 0; it < 2; ++it) {
        int idx = it * 256 + tid;
        int p = idx >> 3, ch = idx & 7;
        int o = p * 33 + ch * 4;
        uint4 v = make_uint4(lt[o], lt[o + 1], lt[o + 2], lt[o + 3]);
        *(uint4*)(xT + ((size_t)(b * (HH * WW) + p0 + p) * 64 + ch * 8)) = v;
    }
    {
        int cp = tid & 31, grp = tid >> 5;
        float s0 = 0.f, s1 = 0.f;
        #pragma unroll
        for (int j2 = 0; j2 < 8; ++j2) {
            unsigned u = lt[(grp * 8 + j2) * 33 + cp];
            s0 += __builtin_bit_cast(float, u << 16);
            s1 += __builtin_bit_cast(float, u & 0xffff0000u);
        }
        red[grp][cp][0] = s0;
        red[grp][cp][1] = s1;
    }
    __syncthreads();
    if (tid < 64) {
        float s = 0.f;
        #pragma unroll
        for (int g2 = 0; g2 < 8; ++g2) s += red[g2][tid >> 1][tid & 1];
        partials[(size_t)(b * 256 + pt) * 64 + tid] = s;
    }
}

// ---------------- kernel C: fused MLP + main dynamic conv (counted-vmcnt) ----
// Best-known configuration (R16): 512 blocks x 4 tasks, b = id&7 XCD affinity,
// async global_load_lds staging (linear LDS dest + pre-swizzled source),
// fused MLP prologue hiding task-0 DMA, single merged 4-row compute pass
// (36 ds_read_b128/wave-task), counted-vmcnt barriers (stores stay in flight).
__global__ __launch_bounds__(256, 2) void main_kernel(
    const unsigned short* __restrict__ xT, const float* __restrict__ atw1,
    const unsigned short* __restrict__ W3, const float* __restrict__ partials,
    const float* __restrict__ a2w1, const float* __restrict__ a2b1,
    const float* __restrict__ a2w2, const float* __restrict__ a2b2,
    const float* __restrict__ a3w1, const float* __restrict__ a3b1,
    const float* __restrict__ a3w2, const float* __restrict__ a3b2,
    float* __restrict__ out, const float* __restrict__ zpage) {
    const int id = blockIdx.x;
    const int b = id & 7;
    const int j = id >> 3;        // 0..63 -> tasks j*4 .. j*4+3
    const int tid = threadIdx.x;
    const int lane = tid & 63;
    const int wtile = tid >> 6;   // wave id (uniform per wave)
    const int lm = lane & 15;
    const int lk = lane >> 4;

    __shared__ char xsc[2][16384];        // 1024 slots x 16B (slack 864..1023)
    __shared__ float alds[2][768];        // 768 slots x 4B (slack 576..767)
    __shared__ float rb[4][64];
    __shared__ float gs[64], h3[64], h2[12], rrs[12], bbs[64];

    const char* xbb = (const char*)(xT + (size_t)b * (HH * WW) * 64);
    const float* ab = atw1 + (size_t)b * 9 * (HH * WW);
    float* ob = out + (size_t)b * 64 * (HH * WW);
    const char* zp = (const char*)zpage;

    // ---- async stage of one task into buffer bi (7 DMA issues per thread) ----
    auto STAGE = [&](int bi, int task) {
        const int py0 = (task >> 3) * TH, px0 = (task & 7) * TW;
        #pragma unroll
        for (int i = 0; i < 4; ++i) {
            int idx = i * 256 + tid;               // slot = dest/16
            int pix = idx >> 3, ch = idx & 7;
            int yy = pix / HALOW;
            int xx = pix - yy * HALOW;
            int gy = py0 + yy - 1, gx = px0 + xx - 1;
            bool ok = (pix < NPIX) && (gy >= 0) && (gy < HH) && (gx >= 0) && (gx < WW);
            const char* src = ok
                ? xbb + (((size_t)(gy * WW + gx)) << 7) + ((ch * 16) ^ ((pix & 7) << 4))
                : zp;
            char* dst = &xsc[bi][(i * 256 + wtile * 64) * 16];   // uniform base + lane*16
            __builtin_amdgcn_global_load_lds((glds_src_t*)src, (glds_dst_t*)dst, 16, 0, 0);
        }
        #pragma unroll
        for (int i = 0; i < 3; ++i) {
            int idx = i * 256 + tid;
            int t = idx >> 6, rem = idx & 63;
            int rr = rem >> 4, cc = rem & 15;
            bool ok = idx < NA;
            const char* src = ok
                ? (const char*)(ab + (size_t)t * (HH * WW) + (py0 + rr) * WW + px0 + cc)
                : zp;
            float* dst = &alds[bi][i * 256 + wtile * 64];
            __builtin_amdgcn_global_load_lds((glds_src_t*)src, (glds_dst_t*)dst, 4, 0, 0);
        }
    };

    // ---- prologue DMA first: MLP compute below hides its latency ----
    STAGE(0, j * 4);

    // ---- W fragments: 18 coalesced b128 loads ----
    short8 wfrag[9][2];
    {
        const short8* W3v = (const short8*)W3;
        #pragma unroll
        for (int t = 0; t < 9; ++t)
            #pragma unroll
            for (int ks = 0; ks < 2; ++ks)
                wfrag[t][ks] = W3v[(((t * 2 + ks) * 4 + lk) * 64) + wtile * 16 + lm];
    }

    // ---- fused MLP: partials -> g -> ratio (rrs), bias (bbs) ----
    {
        const int t = tid & 63, is = tid >> 6;
        float s = 0.f;
        #pragma unroll 8
        for (int k = 0; k < 64; ++k)
            s += partials[(size_t)(b * 256 + is + 4 * k) * 64 + t];
        rb[is][t] = s;
        __syncthreads();
        if (tid < 64)
            gs[t] = (rb[0][t] + rb[1][t] + rb[2][t] + rb[3][t]) * (1.f / (HH * WW));
        __syncthreads();
        if (tid < 64) {
            float s3 = 0.f;
            #pragma unroll 8
            for (int i = 0; i < 64; ++i) s3 += gs[i] * a3w1[t * 64 + i];
            h3[t] = fmaxf(s3 + a3b1[t], 0.f);
            if (t < 9) {
                float s2 = 0.f;
                #pragma unroll 8
                for (int i = 0; i < 64; ++i) s2 += gs[i] * a2w1[t * 64 + i];
                h2[t] = fmaxf(s2 + a2b1[t], 0.f);
            }
        }
        __syncthreads();
        if (tid < 64) {
            float o = 0.f;
            #pragma unroll 8
            for (int i = 0; i < 64; ++i) o += h3[i] * a3w2[t * 64 + i];
            bbs[t] = o + a3b2[t];
            if (t < 9) {
                float r = 0.f;
                #pragma unroll
                for (int i = 0; i < 9; ++i) r += h2[i] * a2w2[t * 9 + i];
                rrs[t] = r + a2b2[t];
            }
        }
        __syncthreads();   // also drains prologue STAGE (vmcnt 0) -> buf0 ready
    }

    float rat[9];
    #pragma unroll
    for (int t = 0; t < 9; ++t) rat[t] = rrs[t];
    float biasr[4];
    #pragma unroll
    for (int q = 0; q < 4; ++q) biasr[q] = bbs[wtile * 16 + lk * 4 + q];

    #pragma unroll 1
    for (int it = 0; it < 4; ++it) {
        if (it < 3) {
            STAGE((it + 1) & 1, j * 4 + it + 1);   // DMA lands under compute
            __builtin_amdgcn_sched_barrier(0);     // pin: all STAGE issues precede stores
        }

        const int task = j * 4 + it;
        const int py0 = (task >> 3) * TH, px0 = (task & 7) * TW;
        const char* xs = xsc[it & 1];
        const float* al = alds[it & 1];

        // ---- single merged pass: 4 output rows, 6 halo rows, 36 b128 reads ----
        float av[4][9];
        #pragma unroll
        for (int r = 0; r < 4; ++r)
            #pragma unroll
            for (int t = 0; t < 9; ++t)
                av[r][t] = al[t * 64 + r * 16 + lm] * rat[t];

        f32x4 yac[4];
        #pragma unroll
        for (int r = 0; r < 4; ++r) yac[r] = (f32x4){0.f, 0.f, 0.f, 0.f};

        #pragma unroll
        for (int hl = 0; hl < 6; ++hl) {
            const int pixr = hl * HALOW + lm;
            short8 bf[3][2];
            #pragma unroll
            for (int dx = 0; dx < 3; ++dx) {
                const int pix = pixr + dx;
                const int sw = (pix & 7) << 4;
                const char* bp2 = xs + pix * 128;
                #pragma unroll
                for (int ks = 0; ks < 2; ++ks)
                    bf[dx][ks] = __builtin_bit_cast(short8,
                        *(const uint4*)(bp2 + ((ks * 64 + lk * 16) ^ sw)));
            }
            #pragma unroll
            for (int dy = 0; dy < 3; ++dy) {
                const int r = hl - dy;
                if (r < 0 || r > 3) continue;
                #pragma unroll
                for (int dx = 0; dx < 3; ++dx) {
                    const int t = dy * 3 + dx;
                    f32x4 z = {0.f, 0.f, 0.f, 0.f};
                    z = __builtin_amdgcn_mfma_f32_16x16x32_bf16(wfrag[t][0], bf[dx][0], z, 0, 0, 0);
                    z = __builtin_amdgcn_mfma_f32_16x16x32_bf16(wfrag[t][1], bf[dx][1], z, 0, 0, 0);
                    #pragma unroll
                    for (int q = 0; q < 4; ++q) yac[r][q] = fmaf(av[r][t], z[q], yac[r][q]);
                }
            }
        }
        #pragma unroll
        for (int r = 0; r < 4; ++r) {
            const int pyg = py0 + r;
            #pragma unroll
            for (int q = 0; q < 4; ++q) {
                int m = wtile * 16 + lk * 4 + q;   // D: row=(lane>>4)*4+q, col=lane&15
                ob[((size_t)m * HH + pyg) * WW + px0 + lm] = yac[r][q] + biasr[q];
            }
        }

        if (it < 3) {
            // wait only for the 7 staging DMAs (oldest); 16 stores stay in flight
            asm volatile("s_waitcnt vmcnt(16)" ::: "memory");
            __builtin_amdgcn_s_barrier();
            __builtin_amdgcn_sched_barrier(0);
        }
    }
}

extern "C" void kernel_launch(void* const* d_in, const int* in_sizes, int n_in,
                              void* d_out, int out_size, void* d_ws, size_t ws_size,
                              hipStream_t stream) {
    const float* x    = (const float*)d_in[0];
    const float* atw1 = (const float*)d_in[1];
    const float* wgt  = (const float*)d_in[2];
    const float* a2w1 = (const float*)d_in[3];
    const float* a2b1 = (const float*)d_in[4];
    const float* a2w2 = (const float*)d_in[5];
    const float* a2b2 = (const float*)d_in[6];
    const float* a3w1 = (const float*)d_in[7];
    const float* a3b1 = (const float*)d_in[8];
    const float* a3w2 = (const float*)d_in[9];
    const float* a3b2 = (const float*)d_in[10];
    float* out = (float*)d_out;

    float* ws = (float*)d_ws;
    float* zpage = ws + 640;                                // 32 floats (zeroed by prep)
    unsigned short* W3 = (unsigned short*)(ws + 1024);      // 36864 ushorts
    float* partials = ws + 19456;                           // 131072 floats
    unsigned short* xT = (unsigned short*)(ws + 150528);    // 8388608 ushorts (16.8 MB)

    prep_kernel<<<dim3(2048), dim3(256), 0, stream>>>(x, wgt, xT, partials, W3, zpage);
    main_kernel<<<dim3(512), dim3(256), 0, stream>>>(
        xT, atw1, W3, partials, a2w1, a2b1, a2w2, a2b2,
        a3w1, a3b1, a3w2, a3b2, out, zpage);
}